// Round 1
// baseline (635.294 us; speedup 1.0000x reference)
//
#include <hip/hip_runtime.h>
#include <cstdint>
#include <cstddef>

#define B_ 16
#define S_ 64
#define T_ 4096
#define C_ 512
#define H_ 8
#define D_ 64
#define TC 32

// ---------------------------------------------------------------------------
// ws layout (float offsets):
//   qk      [8][512]        @ 0        (4096)
//   qb      [8]             @ 4096
//   att     [B][H][T]       @ 8192     (524288)
//   wsum    [1024][8][512]  @ 532480   (4194304)
//   attnout [1024][512]     @ 4726784  (524288)
// total 5251072 floats ~= 20 MB
// ---------------------------------------------------------------------------
#define WS_QK      0
#define WS_QB      4096
#define WS_ATT     8192
#define WS_WSUM    532480
#define WS_ATTNOUT 4726784

// K1: q = Wq@x + bq; qh = q*1/8; qk[h][c] = sum_d qh[h,d]*Wk[h*64+d, c];
//     qb[h] = sum_d qh[h,d]*bk[h*64+d]
__global__ void k_prep(const float* __restrict__ x, const float* __restrict__ Wq,
                       const float* __restrict__ bq, const float* __restrict__ Wk,
                       const float* __restrict__ bk, float* __restrict__ qk,
                       float* __restrict__ qb) {
  __shared__ float xs[C_];
  __shared__ float part[4][64];
  __shared__ float qh[64];
  int tid = threadIdx.x;
  int h = blockIdx.x;
  xs[tid] = x[tid];
  xs[tid + 256] = x[tid + 256];
  __syncthreads();
  int d = tid & 63, pp = tid >> 6;
  const float* wrow = Wq + (size_t)(h * 64 + d) * C_ + pp * 128;
  const float* xp = xs + pp * 128;
  float s = 0.f;
#pragma unroll 4
  for (int c = 0; c < 128; ++c) s += wrow[c] * xp[c];
  part[pp][d] = s;
  __syncthreads();
  if (tid < 64) {
    float qv = part[0][tid] + part[1][tid] + part[2][tid] + part[3][tid] +
               bq[h * 64 + tid];
    qh[tid] = qv * 0.125f;  // * 1/sqrt(D)
  }
  __syncthreads();
  if (tid == 0) {
    float sb = 0.f;
    for (int dd = 0; dd < 64; ++dd) sb += qh[dd] * bk[h * 64 + dd];
    qb[h] = sb;
  }
  for (int c = tid; c < C_; c += 256) {
    float s2 = 0.f;
#pragma unroll 8
    for (int dd = 0; dd < 64; ++dd)
      s2 += qh[dd] * Wk[(size_t)(h * 64 + dd) * C_ + c];
    qk[h * C_ + c] = s2;
  }
}

// K2a: att[b][h][t] = qb[h] + sum_c qk[h][c]*eh[b][c][t]
// grid (T/256, B), block 256; one t per thread, coalesced along t.
__global__ void k_att(const float* __restrict__ eh, const float* __restrict__ qk,
                      const float* __restrict__ qb, float* __restrict__ att) {
  __shared__ float qkt[C_ * 8];  // [c][h]
  __shared__ float qbs[8];
  int tid = threadIdx.x;
  for (int i = tid; i < C_ * 8; i += 256) {
    int h = i >> 9, c = i & 511;
    qkt[c * 8 + h] = qk[i];
  }
  if (tid < 8) qbs[tid] = qb[tid];
  __syncthreads();
  int t = blockIdx.x * 256 + tid;
  int b = blockIdx.y;
  const float* ehp = eh + (size_t)b * C_ * T_ + t;
  float acc[8];
#pragma unroll
  for (int h = 0; h < 8; ++h) acc[h] = qbs[h];
#pragma unroll 4
  for (int c = 0; c < C_; ++c) {
    float e = ehp[(size_t)c * T_];
    const float4 a0 = *(const float4*)&qkt[c * 8];
    const float4 a1 = *(const float4*)&qkt[c * 8 + 4];
    acc[0] += a0.x * e; acc[1] += a0.y * e; acc[2] += a0.z * e; acc[3] += a0.w * e;
    acc[4] += a1.x * e; acc[5] += a1.y * e; acc[6] += a1.z * e; acc[7] += a1.w * e;
  }
  float* ap = att + (size_t)b * H_ * T_ + t;
#pragma unroll
  for (int h = 0; h < 8; ++h) ap[(size_t)h * T_] = acc[h];
}

// K2b: per (b,s): softmax over att[b,:,start:end], then
//      wsum[n][h][c] = sum_t p[h][t] * eh[b][c][t]
// grid 1024 (n = b*64+s), block 256. eh staged in LDS [tl][c] (stride 513).
__global__ void k_wsum(const float* __restrict__ eh, const float* __restrict__ att,
                       const int* __restrict__ starts, const int* __restrict__ ends,
                       float* __restrict__ wsum) {
  __shared__ float tile[TC * 513];
  __shared__ float pl[8 * TC];
  __shared__ float ms[8], linv[8];
  int tid = threadIdx.x;
  int n = blockIdx.x;
  int b = n >> 6;
  int start = starts[n], end = ends[n];
  int h = tid >> 5, tl = tid & 31;
  const float* ah = att + ((size_t)b * H_ + h) * T_;

  // softmax stats per head over the segment (att is tiny & L2-hot)
  float mloc = -3.0e38f;
  for (int t = start + tl; t < end; t += 32) mloc = fmaxf(mloc, ah[t]);
#pragma unroll
  for (int off = 16; off > 0; off >>= 1)
    mloc = fmaxf(mloc, __shfl_xor(mloc, off, 32));
  float lloc = 0.f;
  for (int t = start + tl; t < end; t += 32) lloc += __expf(ah[t] - mloc);
#pragma unroll
  for (int off = 16; off > 0; off >>= 1) lloc += __shfl_xor(lloc, off, 32);
  if (tl == 0) { ms[h] = mloc; linv[h] = 1.f / lloc; }

  float acc0[8], acc1[8];
#pragma unroll
  for (int i = 0; i < 8; ++i) { acc0[i] = 0.f; acc1[i] = 0.f; }
  int c0 = tid, c1 = tid + 256;
  int cst = tid >> 5;  // staging c base (0..7)
  const float* gbase = eh + (size_t)b * C_ * T_ + (size_t)cst * T_;
  __syncthreads();

  for (int t0 = start; t0 < end; t0 += TC) {
    int t = t0 + tl;
    bool valid = t < end;
    // stage eh[b][c][t0..t0+31] -> tile[tl][c]; lanes walk t => coalesced
    const float* gp = gbase + t;
#pragma unroll 8
    for (int i = 0; i < 64; ++i) {
      float v = valid ? gp[(size_t)i * 8 * T_] : 0.f;
      tile[tl * 513 + cst + i * 8] = v;  // bank = (tl + c) % 32: conflict-free
    }
    // p[h][tl]
    float pv = valid ? __expf(ah[t] - ms[h]) * linv[h] : 0.f;
    pl[h * 32 + tl] = pv;
    __syncthreads();
    // accumulate: thread owns c0=tid, c1=tid+256, all 8 heads
    for (int ttl = 0; ttl < TC; ++ttl) {
      float e0 = tile[ttl * 513 + c0];
      float e1 = tile[ttl * 513 + c1];
      const float* pp = &pl[ttl];
#pragma unroll
      for (int hh = 0; hh < 8; ++hh) {
        float p = pp[hh * 32];
        acc0[hh] += p * e0;
        acc1[hh] += p * e1;
      }
    }
    __syncthreads();
  }
  float* wp = wsum + (size_t)n * (H_ * C_);
#pragma unroll
  for (int hh = 0; hh < 8; ++hh) {
    wp[hh * C_ + c0] = acc0[hh];
    wp[hh * C_ + c1] = acc1[hh];
  }
}

// K3/K4: C[n][y*64+j] = sum_k A[n*aRow + y*aColPerY + k] * Bm[(y*64+j)*512 + k]
//        + bias[y*64+j]
// 64x64 tile per block, 256 threads, 4x4 per thread. K = 512.
__global__ void k_gemm64(const float* __restrict__ A, long aRow, long aColPerY,
                         const float* __restrict__ Bm,
                         const float* __restrict__ bias, float* __restrict__ Cc) {
  __shared__ float As[64 * 33];
  __shared__ float Bs[64 * 33];
  int tid = threadIdx.x;
  int n0 = blockIdx.x * 64;
  int y = blockIdx.y;
  const float* Abase = A + (size_t)n0 * aRow + (size_t)y * aColPerY;
  const float* Bbase = Bm + (size_t)(y * 64) * C_;
  int tx = tid & 15, ty = tid >> 4;
  float acc[4][4];
#pragma unroll
  for (int a = 0; a < 4; ++a)
#pragma unroll
    for (int bb = 0; bb < 4; ++bb) acc[a][bb] = 0.f;
  for (int k0 = 0; k0 < 512; k0 += 32) {
#pragma unroll
    for (int i = 0; i < 8; ++i) {
      int idx = tid + i * 256;
      int r = idx >> 5, cc = idx & 31;
      As[r * 33 + cc] = Abase[(size_t)r * aRow + k0 + cc];
      Bs[r * 33 + cc] = Bbase[(size_t)r * C_ + k0 + cc];
    }
    __syncthreads();
#pragma unroll 8
    for (int k = 0; k < 32; ++k) {
      float av[4], bv[4];
#pragma unroll
      for (int a = 0; a < 4; ++a) av[a] = As[(ty * 4 + a) * 33 + k];
#pragma unroll
      for (int bb = 0; bb < 4; ++bb) bv[bb] = Bs[(tx * 4 + bb) * 33 + k];
#pragma unroll
      for (int a = 0; a < 4; ++a)
#pragma unroll
        for (int bb = 0; bb < 4; ++bb) acc[a][bb] += av[a] * bv[bb];
    }
    __syncthreads();
  }
#pragma unroll
  for (int a = 0; a < 4; ++a) {
    int nn = n0 + ty * 4 + a;
    float4 o;
    o.x = acc[a][0] + bias[y * 64 + tx * 4 + 0];
    o.y = acc[a][1] + bias[y * 64 + tx * 4 + 1];
    o.z = acc[a][2] + bias[y * 64 + tx * 4 + 2];
    o.w = acc[a][3] + bias[y * 64 + tx * 4 + 3];
    *(float4*)&Cc[(size_t)nn * C_ + y * 64 + tx * 4] = o;
  }
}

extern "C" void kernel_launch(void* const* d_in, const int* in_sizes, int n_in,
                              void* d_out, int out_size, void* d_ws,
                              size_t ws_size, hipStream_t stream) {
  const float* x = (const float*)d_in[0];
  const float* eh = (const float*)d_in[1];
  const int* shot_starts = (const int*)d_in[2];
  const int* shot_ends = (const int*)d_in[3];
  const float* Wq = (const float*)d_in[4];
  const float* bq = (const float*)d_in[5];
  const float* Wk = (const float*)d_in[6];
  const float* bk = (const float*)d_in[7];
  const float* Wv = (const float*)d_in[8];
  const float* bv = (const float*)d_in[9];
  const float* Wp = (const float*)d_in[10];
  const float* bp = (const float*)d_in[11];
  float* out = (float*)d_out;

  float* ws = (float*)d_ws;
  float* qk = ws + WS_QK;
  float* qb = ws + WS_QB;
  float* att = ws + WS_ATT;
  float* wsum = ws + WS_WSUM;
  float* attnout = ws + WS_ATTNOUT;

  k_prep<<<8, 256, 0, stream>>>(x, Wq, bq, Wk, bk, qk, qb);
  k_att<<<dim3(T_ / 256, B_), 256, 0, stream>>>(eh, qk, qb, att);
  k_wsum<<<B_ * S_, 256, 0, stream>>>(eh, att, shot_starts, shot_ends, wsum);
  // attnout[n][h*64+j] = sum_c wsum[n][h][c]*Wv[h*64+j][c] + bv
  k_gemm64<<<dim3(16, 8), 256, 0, stream>>>(wsum, (long)(H_ * C_), (long)C_, Wv,
                                            bv, attnout);
  // out[n][o] = sum_hd attnout[n][hd]*Wp[o][hd] + bp
  k_gemm64<<<dim3(16, 8), 256, 0, stream>>>(attnout, (long)C_, 0L, Wp, bp, out);
}

// Round 2
// 396.733 us; speedup vs baseline: 1.6013x; 1.6013x over previous
//
#include <hip/hip_runtime.h>
#include <cstdint>
#include <cstddef>

#define B_ 16
#define S_ 64
#define T_ 4096
#define C_ 512
#define H_ 8

// ws layout (float offsets):
//   qkT     [512][8]        @ 0        (4096)   transposed: qkT[c*8+h]
//   qb      [8]             @ 4096
//   att     [B][H][T]       @ 8192     (524288)
//   wsum    [1024][8][512]  @ 532480   (4194304)
//   attnout [1024][512]     @ 4726784  (524288)
#define WS_QKT     0
#define WS_QB      4096
#define WS_ATT     8192
#define WS_WSUM    532480
#define WS_ATTNOUT 4726784

// K1: q = Wq@x + bq; qh = q/8; qkT[c][h] = sum_d qh[h,d]*Wk[h*64+d, c];
//     qb[h] = sum_d qh[h,d]*bk[h*64+d]
__global__ void k_prep(const float* __restrict__ x, const float* __restrict__ Wq,
                       const float* __restrict__ bq, const float* __restrict__ Wk,
                       const float* __restrict__ bk, float* __restrict__ qkT,
                       float* __restrict__ qb) {
  __shared__ float xs[C_];
  __shared__ float part[4][64];
  __shared__ float qh[64];
  int tid = threadIdx.x;
  int h = blockIdx.x;
  xs[tid] = x[tid];
  xs[tid + 256] = x[tid + 256];
  __syncthreads();
  int d = tid & 63, pp = tid >> 6;
  const float* wrow = Wq + (size_t)(h * 64 + d) * C_ + pp * 128;
  const float* xp = xs + pp * 128;
  float s = 0.f;
#pragma unroll 4
  for (int c = 0; c < 128; ++c) s += wrow[c] * xp[c];
  part[pp][d] = s;
  __syncthreads();
  if (tid < 64) {
    float qv = part[0][tid] + part[1][tid] + part[2][tid] + part[3][tid] +
               bq[h * 64 + tid];
    qh[tid] = qv * 0.125f;  // * 1/sqrt(D)
  }
  __syncthreads();
  if (tid == 0) {
    float sb = 0.f;
    for (int dd = 0; dd < 64; ++dd) sb += qh[dd] * bk[h * 64 + dd];
    qb[h] = sb;
  }
  for (int c = tid; c < C_; c += 256) {
    float s2 = 0.f;
#pragma unroll 8
    for (int dd = 0; dd < 64; ++dd)
      s2 += qh[dd] * Wk[(size_t)(h * 64 + dd) * C_ + c];
    qkT[c * 8 + h] = s2;
  }
}

// K2: att[b][h][t] = qb[h] + sum_c qkT[c][h]*eh[b][c][t]
// grid (64, 16), block 256: 64 t per block, 4 c-slices of 128.
__global__ __launch_bounds__(256, 4) void k_att(
    const float* __restrict__ eh, const float* __restrict__ qkT,
    const float* __restrict__ qb, float* __restrict__ att) {
  __shared__ float qks[C_ * 8];      // 16 KB
  __shared__ float part[4 * 8 * 64]; // 8 KB [cg][h][tl]
  int tid = threadIdx.x;
  int tl = tid & 63, cg = tid >> 6;
  int b = blockIdx.y;
  int t0 = blockIdx.x * 64;
#pragma unroll
  for (int i = 0; i < 16; ++i) qks[tid + i * 256] = qkT[tid + i * 256];
  __syncthreads();
  const float* ehp = eh + ((size_t)b * C_ + (size_t)cg * 128) * T_ + t0 + tl;
  float acc[8];
#pragma unroll
  for (int h = 0; h < 8; ++h) acc[h] = 0.f;
#pragma unroll 4
  for (int j = 0; j < 128; ++j) {
    float e = ehp[(size_t)j * T_];
    const float4 q0 = *(const float4*)&qks[(cg * 128 + j) * 8];
    const float4 q1 = *(const float4*)&qks[(cg * 128 + j) * 8 + 4];
    acc[0] += q0.x * e; acc[1] += q0.y * e; acc[2] += q0.z * e; acc[3] += q0.w * e;
    acc[4] += q1.x * e; acc[5] += q1.y * e; acc[6] += q1.z * e; acc[7] += q1.w * e;
  }
#pragma unroll
  for (int h = 0; h < 8; ++h) part[(cg * 8 + h) * 64 + tl] = acc[h];
  __syncthreads();
#pragma unroll
  for (int i = 0; i < 2; ++i) {
    int idx = tid + i * 256;
    int h = idx >> 6, tt = idx & 63;
    float v = part[(0 * 8 + h) * 64 + tt] + part[(1 * 8 + h) * 64 + tt] +
              part[(2 * 8 + h) * 64 + tt] + part[(3 * 8 + h) * 64 + tt] + qb[h];
    att[((size_t)b * H_ + h) * T_ + t0 + tt] = v;
  }
}

// K3: per (b,s): softmax stats from att, then
//     wsum[n][h][c] = sum_{t in seg} p[h][t]*eh[b][c][t]
// grid 1024, block 256. Thread owns c0=tid, c1=tid+256, walks t in float4.
__global__ __launch_bounds__(256, 4) void k_wsum(
    const float* __restrict__ eh, const float* __restrict__ att,
    const int* __restrict__ starts, const int* __restrict__ ends,
    float* __restrict__ wsum) {
  __shared__ float pl[8 * 64];  // [h][tloc]
  __shared__ float ms[8], li[8];
  int tid = threadIdx.x;
  int n = blockIdx.x;
  int b = n >> 6;
  int start = starts[n], end = ends[n];
  int h = tid >> 5, tl = tid & 31;
  const float* ah = att + ((size_t)b * H_ + h) * T_;

  float mloc = -3.0e38f;
  for (int t = start + tl; t < end; t += 32) mloc = fmaxf(mloc, ah[t]);
#pragma unroll
  for (int off = 16; off > 0; off >>= 1)
    mloc = fmaxf(mloc, __shfl_xor(mloc, off, 32));
  float lloc = 0.f;
  for (int t = start + tl; t < end; t += 32) lloc += __expf(ah[t] - mloc);
#pragma unroll
  for (int off = 16; off > 0; off >>= 1) lloc += __shfl_xor(lloc, off, 32);
  if (tl == 0) { ms[h] = mloc; li[h] = 1.f / lloc; }

  float acc0[8], acc1[8];
#pragma unroll
  for (int i = 0; i < 8; ++i) { acc0[i] = 0.f; acc1[i] = 0.f; }
  const float* e0p = eh + ((size_t)b * C_ + tid) * T_;
  const float* e1p = e0p + (size_t)256 * T_;
  __syncthreads();

  int tbeg = start & ~3;
  for (int t0 = tbeg; t0 < end; t0 += 64) {
    // stage p for tile [t0, t0+64)
#pragma unroll
    for (int i = 0; i < 2; ++i) {
      int idx = tid + i * 256;
      int hh = idx >> 6;
      int tt = t0 + (idx & 63);
      float pv = 0.f;
      if (tt >= start && tt < end)
        pv = __expf(att[((size_t)b * H_ + hh) * T_ + tt] - ms[hh]) * li[hh];
      pl[idx] = pv;
    }
    __syncthreads();
    int tend = (t0 + 64 < end) ? t0 + 64 : end;
    for (int t = t0; t < tend; t += 4) {
      float4 e0 = *(const float4*)(e0p + t);
      float4 e1 = *(const float4*)(e1p + t);
      int base = t - t0;
#pragma unroll
      for (int hh = 0; hh < 8; ++hh) {
        const float4 p = *(const float4*)&pl[hh * 64 + base];
        acc0[hh] += p.x * e0.x + p.y * e0.y + p.z * e0.z + p.w * e0.w;
        acc1[hh] += p.x * e1.x + p.y * e1.y + p.z * e1.z + p.w * e1.w;
      }
    }
    __syncthreads();
  }
  float* wp = wsum + (size_t)n * (H_ * C_);
#pragma unroll
  for (int hh = 0; hh < 8; ++hh) {
    wp[hh * C_ + tid] = acc0[hh];
    wp[hh * C_ + 256 + tid] = acc1[hh];
  }
}

// K4/K5: C[n][y*64+j] = sum_k A[n*aRow + y*aColPerY + k]*Bm[(y*64+j)*512+k]
//        + bias[y*64+j].  32x64 tile, 256 threads, 2x4 per thread, K=512.
__global__ __launch_bounds__(256, 4) void k_gemm(
    const float* __restrict__ A, long aRow, long aColPerY,
    const float* __restrict__ Bm, const float* __restrict__ bias,
    float* __restrict__ Cc) {
  __shared__ float As[32 * 36];
  __shared__ float Bs[64 * 36];
  int tid = threadIdx.x;
  int n0 = blockIdx.x * 32;
  int y = blockIdx.y;
  const float* Abase = A + (size_t)n0 * aRow + (size_t)y * aColPerY;
  const float* Bbase = Bm + (size_t)(y * 64) * C_;
  int tx = tid & 15, ty = tid >> 4;
  float acc[2][4];
#pragma unroll
  for (int a = 0; a < 2; ++a)
#pragma unroll
    for (int bb = 0; bb < 4; ++bb) acc[a][bb] = 0.f;
  for (int k0 = 0; k0 < 512; k0 += 32) {
#pragma unroll
    for (int i = 0; i < 4; ++i) {
      int idx = tid + i * 256;
      int r = idx >> 5, cc = idx & 31;
      As[r * 36 + cc] = Abase[(size_t)r * aRow + k0 + cc];
    }
#pragma unroll
    for (int i = 0; i < 8; ++i) {
      int idx = tid + i * 256;
      int r = idx >> 5, cc = idx & 31;
      Bs[r * 36 + cc] = Bbase[(size_t)r * C_ + k0 + cc];
    }
    __syncthreads();
#pragma unroll
    for (int k = 0; k < 32; k += 4) {
      const float4 a0 = *(const float4*)&As[(ty * 2 + 0) * 36 + k];
      const float4 a1 = *(const float4*)&As[(ty * 2 + 1) * 36 + k];
#pragma unroll
      for (int bb = 0; bb < 4; ++bb) {
        const float4 bv = *(const float4*)&Bs[(tx * 4 + bb) * 36 + k];
        acc[0][bb] += a0.x * bv.x + a0.y * bv.y + a0.z * bv.z + a0.w * bv.w;
        acc[1][bb] += a1.x * bv.x + a1.y * bv.y + a1.z * bv.z + a1.w * bv.w;
      }
    }
    __syncthreads();
  }
#pragma unroll
  for (int a = 0; a < 2; ++a) {
    int nn = n0 + ty * 2 + a;
    float4 o;
    o.x = acc[a][0] + bias[y * 64 + tx * 4 + 0];
    o.y = acc[a][1] + bias[y * 64 + tx * 4 + 1];
    o.z = acc[a][2] + bias[y * 64 + tx * 4 + 2];
    o.w = acc[a][3] + bias[y * 64 + tx * 4 + 3];
    *(float4*)&Cc[(size_t)nn * C_ + y * 64 + tx * 4] = o;
  }
}

extern "C" void kernel_launch(void* const* d_in, const int* in_sizes, int n_in,
                              void* d_out, int out_size, void* d_ws,
                              size_t ws_size, hipStream_t stream) {
  const float* x = (const float*)d_in[0];
  const float* eh = (const float*)d_in[1];
  const int* shot_starts = (const int*)d_in[2];
  const int* shot_ends = (const int*)d_in[3];
  const float* Wq = (const float*)d_in[4];
  const float* bq = (const float*)d_in[5];
  const float* Wk = (const float*)d_in[6];
  const float* bk = (const float*)d_in[7];
  const float* Wv = (const float*)d_in[8];
  const float* bv = (const float*)d_in[9];
  const float* Wp = (const float*)d_in[10];
  const float* bp = (const float*)d_in[11];
  float* out = (float*)d_out;

  float* ws = (float*)d_ws;
  float* qkT = ws + WS_QKT;
  float* qb = ws + WS_QB;
  float* att = ws + WS_ATT;
  float* wsum = ws + WS_WSUM;
  float* attnout = ws + WS_ATTNOUT;

  k_prep<<<8, 256, 0, stream>>>(x, Wq, bq, Wk, bk, qkT, qb);
  k_att<<<dim3(T_ / 64, B_), 256, 0, stream>>>(eh, qkT, qb, att);
  k_wsum<<<B_ * S_, 256, 0, stream>>>(eh, att, shot_starts, shot_ends, wsum);
  // attnout[n][h*64+d] = sum_c wsum[n][h][c]*Wv[h*64+d][c] + bv
  k_gemm<<<dim3(32, 8), 256, 0, stream>>>(wsum, (long)(H_ * C_), (long)C_, Wv,
                                          bv, attnout);
  // out[n][o] = sum_hd attnout[n][hd]*Wp[o][hd] + bp
  k_gemm<<<dim3(32, 8), 256, 0, stream>>>(attnout, (long)C_, 0L, Wp, bp, out);
}